// Round 1
// 2996.991 us; speedup vs baseline: 1.6416x; 1.6416x over previous
//
#include <hip/hip_runtime.h>

typedef __attribute__((ext_vector_type(8))) short short8;
typedef __attribute__((ext_vector_type(4))) float f32x4;
typedef unsigned long long u64;

__device__ __forceinline__ unsigned short f2bf(float f) {
  unsigned u = __builtin_bit_cast(unsigned, f);
  u += 0x7fffu + ((u >> 16) & 1u);           // round-to-nearest-even
  return (unsigned short)(u >> 16);
}

__device__ __forceinline__ float fast_tanh(float x) {
  float e = __expf(2.0f * x);
  return 1.0f - __fdividef(2.0f, e + 1.0f);
}

// ---------------------------------------------------------------------------
// Generic C = A(fp32)[M,K] @ B(fp32)[K,N] + bias, via bf16 MFMA 16x16x32.
// 128x128 tile, BK=32, 256 threads (4 waves in 2x2, each 64x64 = 4x4 frags).
// (unchanged from previous round)
// ---------------------------------------------------------------------------
__global__ __launch_bounds__(256) void gemm_bias(
    const float* __restrict__ A, const float* __restrict__ B,
    const float* __restrict__ bias, float* __restrict__ C,
    int M, int N, int K)
{
  __shared__ short a_lds[128 * 32];
  __shared__ short b_lds[32 * 128];
  const int tid = threadIdx.x;
  const int lane = tid & 63;
  const int w = tid >> 6;
  const int wm = w >> 1, wn = w & 1;
  const long m0 = (long)blockIdx.x * 128;
  const int n0 = blockIdx.y * 128;

  f32x4 acc[4][4];
#pragma unroll
  for (int i = 0; i < 4; ++i)
#pragma unroll
    for (int j = 0; j < 4; ++j) acc[i][j] = (f32x4){0.f, 0.f, 0.f, 0.f};

  for (int k0 = 0; k0 < K; k0 += 32) {
#pragma unroll
    for (int it = 0; it < 2; ++it) {
      int tsk = tid + (it << 8);
      int r = tsk >> 2;
      int kg = tsk & 3;
      const float* src = A + (m0 + r) * (long)K + (k0 + kg * 8);
      float4 f0 = *(const float4*)src;
      float4 f1 = *(const float4*)(src + 4);
      short8 v;
      v[0] = f2bf(f0.x); v[1] = f2bf(f0.y); v[2] = f2bf(f0.z); v[3] = f2bf(f0.w);
      v[4] = f2bf(f1.x); v[5] = f2bf(f1.y); v[6] = f2bf(f1.z); v[7] = f2bf(f1.w);
      *(short8*)&a_lds[(((r >> 4) * 64) + kg * 16 + (r & 15)) * 8] = v;
    }
#pragma unroll
    for (int rep = 0; rep < 2; ++rep) {
      int nl = tid & 127;
      int kg = (tid >> 7) + rep * 2;
      const float* src = B + (long)(k0 + kg * 8) * N + (n0 + nl);
      short8 v;
#pragma unroll
      for (int r2 = 0; r2 < 8; ++r2) v[r2] = f2bf(src[(long)r2 * N]);
      *(short8*)&b_lds[(((nl >> 4) * 64) + kg * 16 + (nl & 15)) * 8] = v;
    }
    __syncthreads();
    short8 af[4], bfr[4];
#pragma unroll
    for (int mt = 0; mt < 4; ++mt)
      af[mt] = *(const short8*)&a_lds[((wm * 4 + mt) * 64 + lane) * 8];
#pragma unroll
    for (int nt = 0; nt < 4; ++nt)
      bfr[nt] = *(const short8*)&b_lds[((wn * 4 + nt) * 64 + lane) * 8];
#pragma unroll
    for (int mt = 0; mt < 4; ++mt)
#pragma unroll
      for (int nt = 0; nt < 4; ++nt)
        acc[mt][nt] = __builtin_amdgcn_mfma_f32_16x16x32_bf16(
            af[mt], bfr[nt], acc[mt][nt], 0, 0, 0);
    __syncthreads();
  }
#pragma unroll
  for (int nt = 0; nt < 4; ++nt) {
    int col = n0 + wn * 64 + nt * 16 + (lane & 15);
    float bv = bias[col];
#pragma unroll
    for (int mt = 0; mt < 4; ++mt) {
      long row = m0 + wm * 64 + mt * 16 + ((lane >> 4) * 4);
#pragma unroll
      for (int r = 0; r < 4; ++r)
        C[(row + r) * (long)N + col] = acc[mt][nt][r] + bv;
    }
  }
}

// ---------------------------------------------------------------------------
// Persistent RNN scan v2: batch-split into 4 independent sync rings.
//
// h_t[b,:] depends only on h_{t-1}[b,:]  =>  batch rows are independent.
// Grid: 128 wgs x 64 threads (1 wave each).
//   wg = rg*32 + cg:  rg in [0,4) owns batch rows rg*16..+16 (one MFMA M-tile)
//                     cg in [0,32) owns h-columns cg*32..+32 (W slice in LDS)
// Cross-wg traffic only within a row group (32 wgs): each step every wg
// publishes a contiguous [16x32] bf16 chunk (1 KB) and consumes the 32
// chunks of its own row group. Coherence: relaxed AGENT-scope atomics
// (LLC), store-drain via s_waitcnt vmcnt(0) before the flag store —
// same idiom as v1, but 1 barrier/step (intra-wave) instead of 3, and
// 32 KB/step coherent loads per CU instead of 128 KB.
//
// hbuf layout: [2 slots][4 rg][32 cg][16 rows][32 cols] bf16 (256 KB total).
// h_t is written to slot t&1; step t reads h_{t-1} from slot (t&1)^1.
// WAR safety: wg writes h_t (over h_{t-2}) only after observing
// flags[p] >= t for all group peers, i.e. all peers finished step t-1
// including their reads of h_{t-2}. Max drift is 1 step, both directions
// protected by the same flags the consumer already needs.
// flags: 128 entries, padded to 16 B each (2 KB), zeroed at launch.
// ---------------------------------------------------------------------------
__global__ __launch_bounds__(64) void rnn_scan(
    const float* __restrict__ Whh, float* __restrict__ xs,
    unsigned short* __restrict__ hbuf, int* __restrict__ flags)
{
  __shared__ short wlds[32 * 2 * 64 * 8];  // 64 KB: W[:,n0:n0+32] B-frag order
  __shared__ short hstage[16 * 32];        // 1 KB repack buffer
  const int H = 1024;
  const int lane = threadIdx.x;            // 0..63 (one wave)
  const int wg = blockIdx.x;               // 0..127
  const int rg = wg >> 5;                  // row group (batch rows rg*16..+16)
  const int cg = wg & 31;                  // col group (h cols cg*32..+32)
  const int n0 = cg * 32;
  const int r0 = rg * 16;

  // ---- stage W_hh[:, n0:n0+32] once, MFMA B-fragment order ----
  for (int ks = 0; ks < 32; ++ks) {
#pragma unroll
    for (int p = 0; p < 2; ++p) {
      int kg = p * 2 + (lane >> 5);
      int nl = lane & 31;
      const float* src = Whh + (long)(ks * 32 + kg * 8) * H + (n0 + nl);
      short8 v;
#pragma unroll
      for (int r = 0; r < 8; ++r) v[r] = f2bf(src[(long)r * H]);
      int nt = nl >> 4;
      *(short8*)&wlds[(((ks * 2 + nt) * 64) + kg * 16 + (nl & 15)) * 8] = v;
    }
  }
  __syncthreads();

  const int mrow16 = lane & 15;            // A-frag row within 16-row chunk
  const int koff = (lane >> 4) * 8;        // A-frag k offset within 32-k chunk
  const int crow16 = (lane >> 4) << 2;     // C-frag row base within chunk
  const int ncol = lane & 15;              // C-frag col
  const int chunk_rd = mrow16 * 32 + koff; // shorts, 16B-aligned
  const int myflag = (rg * 32 + cg) * 4;   // 16 B padded flags
  union Frag { u64 q[2]; short8 s; };

  for (int t = 0; t < 512; ++t) {
    const int slot_r = (t & 1) ^ 1;        // holds h_{t-1} (zeros at t=0)
    const int slot_w = t & 1;              // receives h_t
    float* xrow = xs + (long)t * 64 * H;

    // xp loads issued before the spin so their latency hides under it
    float xp0[4], xp1[4];
#pragma unroll
    for (int r = 0; r < 4; ++r) {
      xp0[r] = xrow[(long)(r0 + crow16 + r) * H + n0 + ncol];
      xp1[r] = xrow[(long)(r0 + crow16 + r) * H + n0 + 16 + ncol];
    }

    // wait until every producer in my row group has published h_{t-1}
    if (lane < 32) {
      const int* fp = flags + (rg * 32 + lane) * 4;
      while (__hip_atomic_load(fp, __ATOMIC_RELAXED, __HIP_MEMORY_SCOPE_AGENT) < t) {}
    }

    const unsigned short* hrd =
        hbuf + (size_t)slot_r * 65536 + (size_t)rg * 32 * 512;
    f32x4 acc0 = {0.f, 0.f, 0.f, 0.f}, acc1 = {0.f, 0.f, 0.f, 0.f};
#pragma unroll
    for (int p = 0; p < 32; ++p) {
      const u64* src = (const u64*)(hrd + (size_t)p * 512 + chunk_rd);
      Frag a;
      a.q[0] = __hip_atomic_load(src,     __ATOMIC_RELAXED, __HIP_MEMORY_SCOPE_AGENT);
      a.q[1] = __hip_atomic_load(src + 1, __ATOMIC_RELAXED, __HIP_MEMORY_SCOPE_AGENT);
      short8 b0 = *(const short8*)&wlds[((p * 2 + 0) * 64 + lane) * 8];
      short8 b1 = *(const short8*)&wlds[((p * 2 + 1) * 64 + lane) * 8];
      acc0 = __builtin_amdgcn_mfma_f32_16x16x32_bf16(a.s, b0, acc0, 0, 0, 0);
      acc1 = __builtin_amdgcn_mfma_f32_16x16x32_bf16(a.s, b1, acc1, 0, 0, 0);
    }

    // tanh, states (plain fp32, in-place over xp), stage bf16 chunk in LDS
#pragma unroll
    for (int r = 0; r < 4; ++r) {
      float h0 = fast_tanh(acc0[r] + xp0[r]);
      float h1 = fast_tanh(acc1[r] + xp1[r]);
      xrow[(long)(r0 + crow16 + r) * H + n0 + ncol] = h0;
      xrow[(long)(r0 + crow16 + r) * H + n0 + 16 + ncol] = h1;
      hstage[(crow16 + r) * 32 + ncol] = (short)f2bf(h0);
      hstage[(crow16 + r) * 32 + ncol + 16] = (short)f2bf(h1);
    }
    __syncthreads();   // intra-wave: orders hstage writes before readback

    // publish contiguous 1 KB chunk: 16 B per lane, coherent 8 B stores
    unsigned short* hwr =
        hbuf + (size_t)slot_w * 65536 + (size_t)(rg * 32 + cg) * 512;
    {
      const u64* ssrc = (const u64*)&hstage[(lane >> 2) * 32 + (lane & 3) * 8];
      u64 v0 = ssrc[0], v1 = ssrc[1];
      u64* dst = (u64*)(hwr + (lane >> 2) * 32 + (lane & 3) * 8);
      __hip_atomic_store(dst,     v0, __ATOMIC_RELAXED, __HIP_MEMORY_SCOPE_AGENT);
      __hip_atomic_store(dst + 1, v1, __ATOMIC_RELAXED, __HIP_MEMORY_SCOPE_AGENT);
    }
    // drain stores to the coherence point, then raise the flag
    asm volatile("s_waitcnt vmcnt(0)" ::: "memory");
    if (lane == 0)
      __hip_atomic_store(flags + myflag, t + 1,
                         __ATOMIC_RELAXED, __HIP_MEMORY_SCOPE_AGENT);
    // next iteration's hstage writes are ordered after this iteration's
    // reads by in-order per-wave DS execution; no extra barrier needed.
  }
}

extern "C" void kernel_launch(void* const* d_in, const int* in_sizes, int n_in,
                              void* d_out, int out_size, void* d_ws, size_t ws_size,
                              hipStream_t stream)
{
  const float* X   = (const float*)d_in[0];  // [512,64,512]
  const float* Wxh = (const float*)d_in[1];  // [512,1024]
  const float* Whh = (const float*)d_in[2];  // [1024,1024]
  const float* bh  = (const float*)d_in[3];  // [1024]
  const float* Whq = (const float*)d_in[4];  // [1024,512]
  const float* bq  = (const float*)d_in[5];  // [512]

  float* outputs = (float*)d_out;                       // [512,64,512]
  float* states  = outputs + (long)512 * 64 * 512;      // [512,64,1024]

  unsigned short* hbuf = (unsigned short*)d_ws;                 // 2*64*1024 bf16
  int* flags = (int*)((char*)d_ws + (size_t)2 * 64 * 1024 * 2); // 128 padded ints

  hipMemsetAsync(d_ws, 0, (size_t)2 * 64 * 1024 * 2 + 2048, stream);

  // phase 1: Xproj = X @ W_xh + b_h  -> states region (consumed in-place)
  dim3 g1(32768 / 128, 1024 / 128);
  gemm_bias<<<g1, 256, 0, stream>>>(X, Wxh, bh, states, 32768, 1024, 512);

  // phase 2: sequential scan, 4 independent rings of 32 single-wave wgs
  rnn_scan<<<128, 64, 0, stream>>>(Whh, states, hbuf, flags);

  // phase 3: outputs = states @ W_hq + b_q
  dim3 g3(32768 / 128, 512 / 128);
  gemm_bias<<<g3, 256, 0, stream>>>(states, Whq, bq, outputs, 32768, 512, 1024);
}

// Round 2
// 2383.042 us; speedup vs baseline: 2.0646x; 1.2576x over previous
//
#include <hip/hip_runtime.h>

typedef __attribute__((ext_vector_type(8))) short short8;
typedef __attribute__((ext_vector_type(4))) float f32x4;
typedef __attribute__((ext_vector_type(4))) int i32x4;
typedef unsigned long long u64;

__device__ __forceinline__ unsigned short f2bf(float f) {
  unsigned u = __builtin_bit_cast(unsigned, f);
  u += 0x7fffu + ((u >> 16) & 1u);           // round-to-nearest-even
  return (unsigned short)(u >> 16);
}

__device__ __forceinline__ float fast_tanh(float x) {
  float e = __expf(2.0f * x);
  return 1.0f - __fdividef(2.0f, e + 1.0f);
}

// ---------------------------------------------------------------------------
// Generic C = A(fp32)[M,K] @ B(fp32)[K,N] + bias, via bf16 MFMA 16x16x32.
// 128x128 tile, BK=32, 256 threads (4 waves in 2x2, each 64x64 = 4x4 frags).
// (unchanged)
// ---------------------------------------------------------------------------
__global__ __launch_bounds__(256) void gemm_bias(
    const float* __restrict__ A, const float* __restrict__ B,
    const float* __restrict__ bias, float* __restrict__ C,
    int M, int N, int K)
{
  __shared__ short a_lds[128 * 32];
  __shared__ short b_lds[32 * 128];
  const int tid = threadIdx.x;
  const int lane = tid & 63;
  const int w = tid >> 6;
  const int wm = w >> 1, wn = w & 1;
  const long m0 = (long)blockIdx.x * 128;
  const int n0 = blockIdx.y * 128;

  f32x4 acc[4][4];
#pragma unroll
  for (int i = 0; i < 4; ++i)
#pragma unroll
    for (int j = 0; j < 4; ++j) acc[i][j] = (f32x4){0.f, 0.f, 0.f, 0.f};

  for (int k0 = 0; k0 < K; k0 += 32) {
#pragma unroll
    for (int it = 0; it < 2; ++it) {
      int tsk = tid + (it << 8);
      int r = tsk >> 2;
      int kg = tsk & 3;
      const float* src = A + (m0 + r) * (long)K + (k0 + kg * 8);
      float4 f0 = *(const float4*)src;
      float4 f1 = *(const float4*)(src + 4);
      short8 v;
      v[0] = f2bf(f0.x); v[1] = f2bf(f0.y); v[2] = f2bf(f0.z); v[3] = f2bf(f0.w);
      v[4] = f2bf(f1.x); v[5] = f2bf(f1.y); v[6] = f2bf(f1.z); v[7] = f2bf(f1.w);
      *(short8*)&a_lds[(((r >> 4) * 64) + kg * 16 + (r & 15)) * 8] = v;
    }
#pragma unroll
    for (int rep = 0; rep < 2; ++rep) {
      int nl = tid & 127;
      int kg = (tid >> 7) + rep * 2;
      const float* src = B + (long)(k0 + kg * 8) * N + (n0 + nl);
      short8 v;
#pragma unroll
      for (int r2 = 0; r2 < 8; ++r2) v[r2] = f2bf(src[(long)r2 * N]);
      *(short8*)&b_lds[(((nl >> 4) * 64) + kg * 16 + (nl & 15)) * 8] = v;
    }
    __syncthreads();
    short8 af[4], bfr[4];
#pragma unroll
    for (int mt = 0; mt < 4; ++mt)
      af[mt] = *(const short8*)&a_lds[((wm * 4 + mt) * 64 + lane) * 8];
#pragma unroll
    for (int nt = 0; nt < 4; ++nt)
      bfr[nt] = *(const short8*)&b_lds[((wn * 4 + nt) * 64 + lane) * 8];
#pragma unroll
    for (int mt = 0; mt < 4; ++mt)
#pragma unroll
      for (int nt = 0; nt < 4; ++nt)
        acc[mt][nt] = __builtin_amdgcn_mfma_f32_16x16x32_bf16(
            af[mt], bfr[nt], acc[mt][nt], 0, 0, 0);
    __syncthreads();
  }
#pragma unroll
  for (int nt = 0; nt < 4; ++nt) {
    int col = n0 + wn * 64 + nt * 16 + (lane & 15);
    float bv = bias[col];
#pragma unroll
    for (int mt = 0; mt < 4; ++mt) {
      long row = m0 + wm * 64 + mt * 16 + ((lane >> 4) * 4);
#pragma unroll
      for (int r = 0; r < 4; ++r)
        C[(row + r) * (long)N + col] = acc[mt][nt][r] + bv;
    }
  }
}

// ---------------------------------------------------------------------------
// Persistent RNN scan v3: transposed MFMA + bursted coherent loads.
//
// Topology unchanged from v2: 128 wgs x 64 threads (1 wave), 4 independent
// rings of 32 wgs; wg = rg*32+cg owns batch rows rg*16..+16, h-cols cg*32..+32.
// hbuf: [2 slots][4 rg][32 cg][16 rows][32 cols] bf16 (256 KB), flags 16B-padded.
//
// v3 changes (all critical-path):
//  (a) Compute D' = W^T (A-op) x h^T (B-op) instead of h x W. The C-frag then
//      holds 4 CONSECUTIVE h-cols of one batch row per lane -> pack4 -> one
//      u64 agent store lands directly in row-major chunk layout. The LDS
//      hstage bounce + barrier + repack are gone. xp/state accesses: float4.
//  (b) Chunk loads: 32x inline-asm global_load_dwordx4 sc0 sc1 into a static
//      register array (128 VGPRs), one vmcnt(0) + sched_barrier(0), then a
//      pure ds_read+MFMA phase. All 32 LLC round trips overlap by construction.
//  (c) fp32 state stores moved after the flag raise -> the pre-flag vmcnt(0)
//      drains only the 2 publish stores.
// B-frag read pattern (row m = lane&15, 8 consecutive k) is identical to the
// old A-frag read, so the chunk format on the wire is unchanged.
// ---------------------------------------------------------------------------
__global__ __launch_bounds__(64, 1) void rnn_scan(
    const float* __restrict__ Whh, float* __restrict__ xs,
    unsigned short* __restrict__ hbuf, int* __restrict__ flags)
{
  __shared__ short wlds[32 * 2 * 64 * 8];  // 64 KB: W^T in MFMA A-frag order
  const int H = 1024;
  const int lane = threadIdx.x;            // 0..63 (one wave)
  const int wg = blockIdx.x;               // 0..127
  const int rg = wg >> 5;                  // ring (batch rows rg*16..+16)
  const int cg = wg & 31;                  // col group (h cols cg*32..+32)
  const int n0 = cg * 32;
  const int r0 = rg * 16;

  // ---- stage W_hh[:, n0:n0+32] as A-frags of W^T ----
  // frag (p, mt): value j at lane = W_hh[p*32 + (lane>>4)*8 + j, n0+mt*16+(lane&15)]
  for (int p = 0; p < 32; ++p) {
#pragma unroll
    for (int mt = 0; mt < 2; ++mt) {
      const float* src = Whh + (long)(p * 32 + (lane >> 4) * 8) * H
                       + (n0 + mt * 16 + (lane & 15));
      short8 v;
#pragma unroll
      for (int j = 0; j < 8; ++j) v[j] = f2bf(src[(long)j * H]);
      *(short8*)&wlds[(((p * 2 + mt) * 64) + lane) * 8] = v;
    }
  }
  __syncthreads();

  const int m = lane & 15;                 // batch row within chunk (B-frag col)
  const int q4 = (lane >> 4) * 4;          // C-frag row base = h-col sub-offset
  const int chunk_rd = m * 32 + (lane >> 4) * 8;  // shorts, 16B-aligned
  const int myflag = wg * 4;               // 16 B padded flags
  union Pack { unsigned short us[4]; u64 q; };

  for (int t = 0; t < 512; ++t) {
    const int slot_r = (t & 1) ^ 1;        // holds h_{t-1} (zeros at t=0)
    const int slot_w = t & 1;              // receives h_t
    float* xrow = xs + (long)t * 64 * H;
    float* xbase = xrow + (long)(r0 + m) * H + n0 + q4;

    // xp loads issued before the spin so their latency hides under it
    f32x4 xp0 = *(const f32x4*)xbase;          // cols n0+q4 .. +3      (mt=0)
    f32x4 xp1 = *(const f32x4*)(xbase + 16);   // cols n0+16+q4 .. +3   (mt=1)

    // wait until every producer in my ring has published h_{t-1}
    if (lane < 32) {
      const int* fp = flags + (rg * 32 + lane) * 4;
      while (__hip_atomic_load(fp, __ATOMIC_RELAXED, __HIP_MEMORY_SCOPE_AGENT) < t) {}
    }

    // burst all 32 chunk loads (16 B/lane each) -> registers, LLC-coherent
    const unsigned short* hrd =
        hbuf + (size_t)slot_r * 65536 + (size_t)rg * 16384 + chunk_rd;
    i32x4 hraw[32];
#pragma unroll
    for (int p = 0; p < 32; ++p) {
      asm volatile("global_load_dwordx4 %0, %1, off sc0 sc1"
                   : "=v"(hraw[p]) : "v"(hrd + (size_t)p * 512) : "memory");
    }
    asm volatile("s_waitcnt vmcnt(0)" ::: "memory");
    __builtin_amdgcn_sched_barrier(0);     // rule 18: keep MFMAs below the wait

    f32x4 acc0 = {0.f, 0.f, 0.f, 0.f}, acc1 = {0.f, 0.f, 0.f, 0.f};
#pragma unroll
    for (int p = 0; p < 32; ++p) {
      short8 a0 = *(const short8*)&wlds[((p * 2 + 0) * 64 + lane) * 8];
      short8 a1 = *(const short8*)&wlds[((p * 2 + 1) * 64 + lane) * 8];
      short8 hb = __builtin_bit_cast(short8, hraw[p]);
      acc0 = __builtin_amdgcn_mfma_f32_16x16x32_bf16(a0, hb, acc0, 0, 0, 0);
      acc1 = __builtin_amdgcn_mfma_f32_16x16x32_bf16(a1, hb, acc1, 0, 0, 0);
    }

    // tanh; pack 4 consecutive h-cols per lane -> direct row-major publish
    float h0[4], h1[4];
    Pack pv0, pv1;
#pragma unroll
    for (int r = 0; r < 4; ++r) {
      h0[r] = fast_tanh(acc0[r] + xp0[r]);
      h1[r] = fast_tanh(acc1[r] + xp1[r]);
      pv0.us[r] = f2bf(h0[r]);
      pv1.us[r] = f2bf(h1[r]);
    }
    unsigned short* hwr = hbuf + (size_t)slot_w * 65536 + (size_t)wg * 512;
    __hip_atomic_store((u64*)(hwr + m * 32 + q4), pv0.q,
                       __ATOMIC_RELAXED, __HIP_MEMORY_SCOPE_AGENT);
    __hip_atomic_store((u64*)(hwr + m * 32 + 16 + q4), pv1.q,
                       __ATOMIC_RELAXED, __HIP_MEMORY_SCOPE_AGENT);
    // drain the 2 publish stores to the coherence point, then raise the flag
    asm volatile("s_waitcnt vmcnt(0)" ::: "memory");
    if (lane == 0)
      __hip_atomic_store(flags + myflag, t + 1,
                         __ATOMIC_RELAXED, __HIP_MEMORY_SCOPE_AGENT);

    // fp32 states (for outputs GEMM) — off the critical path
    *(f32x4*)xbase = (f32x4){h0[0], h0[1], h0[2], h0[3]};
    *(f32x4*)(xbase + 16) = (f32x4){h1[0], h1[1], h1[2], h1[3]};
  }
}

extern "C" void kernel_launch(void* const* d_in, const int* in_sizes, int n_in,
                              void* d_out, int out_size, void* d_ws, size_t ws_size,
                              hipStream_t stream)
{
  const float* X   = (const float*)d_in[0];  // [512,64,512]
  const float* Wxh = (const float*)d_in[1];  // [512,1024]
  const float* Whh = (const float*)d_in[2];  // [1024,1024]
  const float* bh  = (const float*)d_in[3];  // [1024]
  const float* Whq = (const float*)d_in[4];  // [1024,512]
  const float* bq  = (const float*)d_in[5];  // [512]

  float* outputs = (float*)d_out;                       // [512,64,512]
  float* states  = outputs + (long)512 * 64 * 512;      // [512,64,1024]

  unsigned short* hbuf = (unsigned short*)d_ws;                 // 2*64*1024 bf16
  int* flags = (int*)((char*)d_ws + (size_t)2 * 64 * 1024 * 2); // 128 padded ints

  hipMemsetAsync(d_ws, 0, (size_t)2 * 64 * 1024 * 2 + 2048, stream);

  // phase 1: Xproj = X @ W_xh + b_h  -> states region (consumed in-place)
  dim3 g1(32768 / 128, 1024 / 128);
  gemm_bias<<<g1, 256, 0, stream>>>(X, Wxh, bh, states, 32768, 1024, 512);

  // phase 2: sequential scan, 4 independent rings of 32 single-wave wgs
  rnn_scan<<<128, 64, 0, stream>>>(Whh, states, hbuf, flags);

  // phase 3: outputs = states @ W_hq + b_q
  dim3 g3(32768 / 128, 512 / 128);
  gemm_bias<<<g3, 256, 0, stream>>>(states, Whq, bq, outputs, 32768, 512, 1024);
}